// Round 1
// baseline (673.725 us; speedup 1.0000x reference)
//
#include <hip/hip_runtime.h>
#include <hip/hip_bf16.h>

// Problem constants (from reference setup_inputs)
constexpr int B_   = 8;       // batch
constexpr int A_   = 120000;  // anchors
constexpr int C_   = 80;      // classes
constexpr int M_   = 32;      // max annotations per image
constexpr int APB  = 256;     // anchors per block
constexpr int C4   = C_ / 4;  // float4s per anchor row of classifications

#define F_ALPHA 0.25f

// ws layout (floats): [0..7] cls_sum, [8..15] reg_sum, (ints) [16..23] num_pos

__device__ __forceinline__ float smooth_l1(float d) {
    // diff <= 1/9 ? 0.5*9*d^2 : d - 0.5/9
    return (d <= (1.0f / 9.0f)) ? 4.5f * d * d : d - (0.5f / 9.0f);
}

__global__ __launch_bounds__(256, 2) void focal_fused(
    const float* __restrict__ cls,   // [B,A,C]
    const float* __restrict__ reg,   // [B,A,4]
    const float* __restrict__ anc,   // [A,4] (anchors[0])
    const float* __restrict__ ann,   // [B,M,5]
    float* __restrict__ cls_sum,     // [B]
    float* __restrict__ reg_sum,     // [B]
    int*   __restrict__ num_pos)     // [B]
{
    __shared__ float s_ann[M_ * 5];
    __shared__ int   s_code[APB];

    const int b   = blockIdx.y;
    const int a0  = blockIdx.x * APB;
    const int tid = threadIdx.x;
    const int na  = min(APB, A_ - a0);

    if (tid < M_ * 5) s_ann[tid] = ann[b * M_ * 5 + tid];
    __syncthreads();

    // ---------------- Phase 1: anchor assignment + reg loss ----------------
    if (tid < na) {
        const int a = a0 + tid;
        const float4 ab = reinterpret_cast<const float4*>(anc)[a];
        const float ax1 = ab.x, ay1 = ab.y, ax2 = ab.z, ay2 = ab.w;
        const float area_a = (ax2 - ax1) * (ay2 - ay1);

        float best = -2.0f;
        int   arg  = 0;
        #pragma unroll 8
        for (int m = 0; m < M_; ++m) {
            const float bx1 = s_ann[m * 5 + 0];
            const float by1 = s_ann[m * 5 + 1];
            const float bx2 = s_ann[m * 5 + 2];
            const float by2 = s_ann[m * 5 + 3];
            const float lab = s_ann[m * 5 + 4];
            float iw = fminf(ax2, bx2) - fmaxf(ax1, bx1);
            iw = fmaxf(iw, 0.0f);
            float ih = fminf(ay2, by2) - fmaxf(ay1, by1);
            ih = fmaxf(ih, 0.0f);
            const float inter  = iw * ih;
            const float area_b = (bx2 - bx1) * (by2 - by1);
            const float ua  = fmaxf(area_a + area_b - inter, 1e-8f);
            float iou = inter / ua;
            if (lab == -1.0f) iou = -1.0f;       // invalid GT never matched
            if (iou > best) { best = iou; arg = m; }   // first-occurrence argmax
        }

        int code;
        if (best >= 0.5f) {
            code = (int)s_ann[arg * 5 + 4];      // assigned class
            // regression loss for this positive anchor
            const float gx1 = s_ann[arg * 5 + 0];
            const float gy1 = s_ann[arg * 5 + 1];
            const float gx2 = s_ann[arg * 5 + 2];
            const float gy2 = s_ann[arg * 5 + 3];
            float gw = gx2 - gx1, gh = gy2 - gy1;
            const float gcx = gx1 + 0.5f * gw;
            const float gcy = gy1 + 0.5f * gh;
            gw = fmaxf(gw, 1.0f);
            gh = fmaxf(gh, 1.0f);
            const float aw  = ax2 - ax1, ah = ay2 - ay1;
            const float acx = ax1 + 0.5f * aw;
            const float acy = ay1 + 0.5f * ah;
            const float t0 = ((gcx - acx) / aw) / 0.1f;
            const float t1 = ((gcy - acy) / ah) / 0.1f;
            const float t2 = logf(gw / aw) / 0.2f;
            const float t3 = logf(gh / ah) / 0.2f;
            const float4 rp = reinterpret_cast<const float4*>(reg)[(size_t)b * A_ + a];
            float rsum = smooth_l1(fabsf(t0 - rp.x))
                       + smooth_l1(fabsf(t1 - rp.y))
                       + smooth_l1(fabsf(t2 - rp.z))
                       + smooth_l1(fabsf(t3 - rp.w));
            atomicAdd(&reg_sum[b], rsum);
            atomicAdd(&num_pos[b], 1);
        } else if (best < 0.4f) {
            code = -1;   // negative: all-zero targets
        } else {
            code = -2;   // ignore band [0.4, 0.5)
        }
        s_code[tid] = code;
    }
    __syncthreads();

    // ---------------- Phase 2: focal classification loss ----------------
    const float4* cp = reinterpret_cast<const float4*>(cls) + ((size_t)b * A_ + a0) * C4;
    const int total = na * C4;
    float acc = 0.0f;
    for (int t = tid; t < total; t += APB) {
        const int la = t / C4;          // local anchor
        const int c4 = t - la * C4;     // float4 index within the row
        const float4 v = cp[t];
        const int code  = s_code[la];
        const int cbase = c4 * 4;
        const float vv[4] = {v.x, v.y, v.z, v.w};
        #pragma unroll
        for (int j = 0; j < 4; ++j) {
            const float p = fminf(fmaxf(vv[j], 1e-4f), 1.0f - 1e-4f);
            const bool is_t = (cbase + j == code);       // target == 1
            // target==1: af=0.25, q=1-p, bce=-log(p)=-log(1-q)
            // target==0: af=0.75, q=p,   bce=-log(1-p)=-log(1-q)
            // ignore (code==-2): af=0 -> contribution 0
            float af = is_t ? F_ALPHA : (1.0f - F_ALPHA);
            if (code == -2) af = 0.0f;
            const float q = is_t ? (1.0f - p) : p;
            acc += af * q * q * (-__logf(1.0f - q));
        }
    }
    // wave reduction (64 lanes), then one atomic per wave
    #pragma unroll
    for (int off = 32; off > 0; off >>= 1) acc += __shfl_down(acc, off, 64);
    if ((tid & 63) == 0) atomicAdd(&cls_sum[b], acc);
}

__global__ void focal_finalize(const float* __restrict__ cls_sum,
                               const float* __restrict__ reg_sum,
                               const int*   __restrict__ num_pos,
                               float* __restrict__ out)
{
    if (threadIdx.x == 0) {
        float cm = 0.0f, rm = 0.0f;
        for (int b = 0; b < B_; ++b) {
            const float np = (float)num_pos[b];
            cm += cls_sum[b] / fmaxf(np, 1.0f);
            rm += (np > 0.0f) ? reg_sum[b] / fmaxf(4.0f * np, 1.0f) : 0.0f;
        }
        out[0] = cm / (float)B_;
        out[1] = rm / (float)B_;
    }
}

extern "C" void kernel_launch(void* const* d_in, const int* in_sizes, int n_in,
                              void* d_out, int out_size, void* d_ws, size_t ws_size,
                              hipStream_t stream) {
    const float* cls = (const float*)d_in[0];   // [B,A,C]
    const float* reg = (const float*)d_in[1];   // [B,A,4]
    const float* anc = (const float*)d_in[2];   // [1,A,4]
    const float* ann = (const float*)d_in[3];   // [B,M,5]
    float* out = (float*)d_out;

    float* wsf     = (float*)d_ws;
    float* cls_sum = wsf;            // 8 floats
    float* reg_sum = wsf + 8;        // 8 floats
    int*   np      = (int*)(wsf + 16); // 8 ints

    hipMemsetAsync(d_ws, 0, 24 * sizeof(float), stream);

    dim3 grid((A_ + APB - 1) / APB, B_);
    focal_fused<<<grid, APB, 0, stream>>>(cls, reg, anc, ann, cls_sum, reg_sum, np);
    focal_finalize<<<1, 64, 0, stream>>>(cls_sum, reg_sum, np, out);
}

// Round 2
// 457.578 us; speedup vs baseline: 1.4724x; 1.4724x over previous
//
#include <hip/hip_runtime.h>
#include <hip/hip_bf16.h>

// Problem constants (from reference setup_inputs)
constexpr int B_   = 8;       // batch
constexpr int A_   = 120000;  // anchors
constexpr int C_   = 80;      // classes
constexpr int M_   = 32;      // max annotations per image
constexpr int APB  = 256;     // anchors per block
constexpr int C4   = C_ / 4;  // float4s per anchor row of classifications

#define F_LN2 0.69314718056f
#define C0_ (0.75f * F_LN2)   // (1-alpha)*ln2  (negatives / non-target classes)
#define C1_ (0.25f * F_LN2)   // alpha*ln2      (target class on positives)

// ws layout (floats): [0..7] cls_sum, [8..15] reg_sum, (ints) [16..23] num_pos

__device__ __forceinline__ float smooth_l1(float d) {
    return (d <= (1.0f / 9.0f)) ? 4.5f * d * d : d - (0.5f / 9.0f);
}

__device__ __forceinline__ float clampp(float x) {
    return fminf(fmaxf(x, 1e-4f), 1.0f - 1e-4f);
}

// focal term for target==0: (1-alpha) * p^2 * (-ln(1-p))
__device__ __forceinline__ float f_neg(float p) {
    return C0_ * p * p * (-__log2f(1.0f - p));
}
// focal term for target==1: alpha * (1-p)^2 * (-ln p)
__device__ __forceinline__ float f_pos(float p) {
    const float q = 1.0f - p;
    return C1_ * q * q * (-__log2f(p));
}

__global__ __launch_bounds__(256) void focal_fused(
    const float* __restrict__ cls,   // [B,A,C]
    const float* __restrict__ reg,   // [B,A,4]
    const float* __restrict__ anc,   // [A,4] (anchors[0])
    const float* __restrict__ ann,   // [B,M,5]
    float* __restrict__ cls_sum,     // [B]
    float* __restrict__ reg_sum,     // [B]
    int*   __restrict__ num_pos)     // [B]
{
    __shared__ float s_ann[M_ * 5];
    __shared__ float s_mask[APB];    // 0.0 = ignore band, 1.0 otherwise
    __shared__ float s_red[2];       // [0]=reg partial, [1]=cls partial
    __shared__ int   s_np;

    const int b   = blockIdx.y;
    const int a0  = blockIdx.x * APB;
    const int tid = threadIdx.x;
    const int na  = min(APB, A_ - a0);

    if (tid < M_ * 5) s_ann[tid] = ann[b * M_ * 5 + tid];
    if (tid == 0) { s_red[0] = 0.0f; s_red[1] = 0.0f; s_np = 0; }
    __syncthreads();

    float acc  = 0.0f;   // this thread's cls-loss partial
    float rsum = 0.0f;   // this thread's reg-loss partial
    int   npos = 0;

    // ---------------- Phase 1: anchor assignment + reg loss + pos correction ----
    if (tid < na) {
        const int a = a0 + tid;
        const float4 ab = reinterpret_cast<const float4*>(anc)[a];
        const float ax1 = ab.x, ay1 = ab.y, ax2 = ab.z, ay2 = ab.w;
        const float area_a = (ax2 - ax1) * (ay2 - ay1);

        float best = -2.0f;
        int   arg  = 0;
        #pragma unroll 8
        for (int m = 0; m < M_; ++m) {
            const float bx1 = s_ann[m * 5 + 0];
            const float by1 = s_ann[m * 5 + 1];
            const float bx2 = s_ann[m * 5 + 2];
            const float by2 = s_ann[m * 5 + 3];
            const float lab = s_ann[m * 5 + 4];
            float iw = fmaxf(fminf(ax2, bx2) - fmaxf(ax1, bx1), 0.0f);
            float ih = fmaxf(fminf(ay2, by2) - fmaxf(ay1, by1), 0.0f);
            const float inter  = iw * ih;
            const float area_b = (bx2 - bx1) * (by2 - by1);
            const float ua = fmaxf(area_a + area_b - inter, 1e-8f);
            float iou = inter / ua;
            if (lab == -1.0f) iou = -1.0f;             // invalid GT never matched
            if (iou > best) { best = iou; arg = m; }   // first-occurrence argmax
        }

        float mask = 1.0f;
        if (best >= 0.5f) {
            const int code = (int)s_ann[arg * 5 + 4];
            // --- regression loss ---
            const float gx1 = s_ann[arg * 5 + 0];
            const float gy1 = s_ann[arg * 5 + 1];
            const float gx2 = s_ann[arg * 5 + 2];
            const float gy2 = s_ann[arg * 5 + 3];
            float gw = gx2 - gx1, gh = gy2 - gy1;
            const float gcx = gx1 + 0.5f * gw;
            const float gcy = gy1 + 0.5f * gh;
            gw = fmaxf(gw, 1.0f);
            gh = fmaxf(gh, 1.0f);
            const float aw  = ax2 - ax1, ah = ay2 - ay1;
            const float acx = ax1 + 0.5f * aw;
            const float acy = ay1 + 0.5f * ah;
            const float t0 = ((gcx - acx) / aw) * 10.0f;
            const float t1 = ((gcy - acy) / ah) * 10.0f;
            const float t2 = logf(gw / aw) * 5.0f;
            const float t3 = logf(gh / ah) * 5.0f;
            const float4 rp = reinterpret_cast<const float4*>(reg)[(size_t)b * A_ + a];
            rsum = smooth_l1(fabsf(t0 - rp.x))
                 + smooth_l1(fabsf(t1 - rp.y))
                 + smooth_l1(fabsf(t2 - rp.z))
                 + smooth_l1(fabsf(t3 - rp.w));
            npos = 1;
            // --- cls correction for the single target class ---
            const float p = clampp(cls[((size_t)b * A_ + a) * C_ + code]);
            acc = f_pos(p) - f_neg(p);   // phase 2 adds f_neg for every class
        } else if (best >= 0.4f) {
            mask = 0.0f;                 // ignore band: whole row contributes 0
        }
        s_mask[tid] = mask;
    }
    __syncthreads();

    // ---------------- Phase 2: branchless streaming focal sum ----------------
    const float4* cp = reinterpret_cast<const float4*>(cls) + ((size_t)b * A_ + a0) * C4;
    const int total = na * C4;
    for (int t = tid; t < total; t += APB) {
        const int la = t / C4;
        const float m = s_mask[la];
        const float4 v = cp[t];
        float s = f_neg(clampp(v.x));
        s += f_neg(clampp(v.y));
        s += f_neg(clampp(v.z));
        s += f_neg(clampp(v.w));
        acc = fmaf(m, s, acc);
    }

    // ---------------- Block reduction: wave shuffle -> LDS -> 3 atomics ------
    #pragma unroll
    for (int off = 32; off > 0; off >>= 1) {
        acc  += __shfl_down(acc,  off, 64);
        rsum += __shfl_down(rsum, off, 64);
        npos += __shfl_down(npos, off, 64);
    }
    if ((tid & 63) == 0) {
        atomicAdd(&s_red[1], acc);
        atomicAdd(&s_red[0], rsum);
        atomicAdd(&s_np, npos);
    }
    __syncthreads();
    if (tid == 0) {
        atomicAdd(&cls_sum[b], s_red[1]);
        atomicAdd(&reg_sum[b], s_red[0]);
        atomicAdd(&num_pos[b], s_np);
    }
}

__global__ void focal_finalize(const float* __restrict__ cls_sum,
                               const float* __restrict__ reg_sum,
                               const int*   __restrict__ num_pos,
                               float* __restrict__ out)
{
    if (threadIdx.x == 0) {
        float cm = 0.0f, rm = 0.0f;
        for (int b = 0; b < B_; ++b) {
            const float np = (float)num_pos[b];
            cm += cls_sum[b] / fmaxf(np, 1.0f);
            rm += (np > 0.0f) ? reg_sum[b] / fmaxf(4.0f * np, 1.0f) : 0.0f;
        }
        out[0] = cm / (float)B_;
        out[1] = rm / (float)B_;
    }
}

extern "C" void kernel_launch(void* const* d_in, const int* in_sizes, int n_in,
                              void* d_out, int out_size, void* d_ws, size_t ws_size,
                              hipStream_t stream) {
    const float* cls = (const float*)d_in[0];   // [B,A,C]
    const float* reg = (const float*)d_in[1];   // [B,A,4]
    const float* anc = (const float*)d_in[2];   // [1,A,4]
    const float* ann = (const float*)d_in[3];   // [B,M,5]
    float* out = (float*)d_out;

    float* wsf     = (float*)d_ws;
    float* cls_sum = wsf;              // 8 floats
    float* reg_sum = wsf + 8;          // 8 floats
    int*   np      = (int*)(wsf + 16); // 8 ints

    hipMemsetAsync(d_ws, 0, 24 * sizeof(float), stream);

    dim3 grid((A_ + APB - 1) / APB, B_);
    focal_fused<<<grid, APB, 0, stream>>>(cls, reg, anc, ann, cls_sum, reg_sum, np);
    focal_finalize<<<1, 64, 0, stream>>>(cls_sum, reg_sum, np, out);
}

// Round 4
// 407.448 us; speedup vs baseline: 1.6535x; 1.1230x over previous
//
#include <hip/hip_runtime.h>
#include <hip/hip_bf16.h>

// Problem constants (from reference setup_inputs)
constexpr int B_   = 8;       // batch
constexpr int A_   = 120000;  // anchors
constexpr int C_   = 80;      // classes
constexpr int M_   = 32;      // max annotations per image
constexpr int APB  = 256;     // anchors per block
constexpr int C4   = C_ / 4;  // float4s per anchor row of classifications
constexpr int GX   = (A_ + APB - 1) / APB;   // 469 blocks per image

#define F_LN2 0.69314718056f
#define C0_ (0.75f * F_LN2)   // (1-alpha)*ln2  (negatives / non-target classes)
#define C1_ (0.25f * F_LN2)   // alpha*ln2      (target class on positives)

typedef float vfloat4 __attribute__((ext_vector_type(4)));  // native vec for nontemporal builtin

// ws layout (floats): P_cls[B*GX] | P_reg[B*GX] | P_np[B*GX]
// Every slot is written unconditionally by its block -> no memset needed.

__device__ __forceinline__ float smooth_l1(float d) {
    return (d <= (1.0f / 9.0f)) ? 4.5f * d * d : d - (0.5f / 9.0f);
}

__device__ __forceinline__ float clampp(float x) {
    return fminf(fmaxf(x, 1e-4f), 1.0f - 1e-4f);
}

// focal term for target==0: (1-alpha) * p^2 * (-ln(1-p))
__device__ __forceinline__ float f_neg(float p) {
    return C0_ * p * p * (-__log2f(1.0f - p));
}
// focal term for target==1: alpha * (1-p)^2 * (-ln p)
__device__ __forceinline__ float f_pos(float p) {
    const float q = 1.0f - p;
    return C1_ * q * q * (-__log2f(p));
}

__global__ __launch_bounds__(256) void focal_fused(
    const float* __restrict__ cls,   // [B,A,C]
    const float* __restrict__ reg,   // [B,A,4]
    const float* __restrict__ anc,   // [A,4] (anchors[0])
    const float* __restrict__ ann,   // [B,M,5]
    float* __restrict__ P_cls,       // [B*GX] per-block partials (no atomics)
    float* __restrict__ P_reg,       // [B*GX]
    float* __restrict__ P_np)        // [B*GX]
{
    __shared__ float s_ann[M_ * 5];
    __shared__ float s_mask[APB];    // 0.0 = ignore band, 1.0 otherwise
    __shared__ float s_red[3][4];    // per-wave partials: [cls|reg|np][wave]

    const int b   = blockIdx.y;
    const int a0  = blockIdx.x * APB;
    const int tid = threadIdx.x;
    const int na  = min(APB, A_ - a0);

    if (tid < M_ * 5) s_ann[tid] = ann[b * M_ * 5 + tid];
    __syncthreads();

    float acc  = 0.0f;   // this thread's cls-loss partial
    float rsum = 0.0f;   // this thread's reg-loss partial
    float npos = 0.0f;

    // ---------------- Phase 1: anchor assignment + reg loss + pos correction ----
    if (tid < na) {
        const int a = a0 + tid;
        const float4 ab = reinterpret_cast<const float4*>(anc)[a];
        const float ax1 = ab.x, ay1 = ab.y, ax2 = ab.z, ay2 = ab.w;
        const float area_a = (ax2 - ax1) * (ay2 - ay1);

        float best = -2.0f;
        int   arg  = 0;
        #pragma unroll 8
        for (int m = 0; m < M_; ++m) {
            const float bx1 = s_ann[m * 5 + 0];
            const float by1 = s_ann[m * 5 + 1];
            const float bx2 = s_ann[m * 5 + 2];
            const float by2 = s_ann[m * 5 + 3];
            const float lab = s_ann[m * 5 + 4];
            float iw = fmaxf(fminf(ax2, bx2) - fmaxf(ax1, bx1), 0.0f);
            float ih = fmaxf(fminf(ay2, by2) - fmaxf(ay1, by1), 0.0f);
            const float inter  = iw * ih;
            const float area_b = (bx2 - bx1) * (by2 - by1);
            const float ua = fmaxf(area_a + area_b - inter, 1e-8f);
            float iou = inter / ua;
            if (lab == -1.0f) iou = -1.0f;             // invalid GT never matched
            if (iou > best) { best = iou; arg = m; }   // first-occurrence argmax
        }

        float mask = 1.0f;
        if (best >= 0.5f) {
            const int code = (int)s_ann[arg * 5 + 4];
            // --- regression loss ---
            const float gx1 = s_ann[arg * 5 + 0];
            const float gy1 = s_ann[arg * 5 + 1];
            const float gx2 = s_ann[arg * 5 + 2];
            const float gy2 = s_ann[arg * 5 + 3];
            float gw = gx2 - gx1, gh = gy2 - gy1;
            const float gcx = gx1 + 0.5f * gw;
            const float gcy = gy1 + 0.5f * gh;
            gw = fmaxf(gw, 1.0f);
            gh = fmaxf(gh, 1.0f);
            const float aw  = ax2 - ax1, ah = ay2 - ay1;
            const float acx = ax1 + 0.5f * aw;
            const float acy = ay1 + 0.5f * ah;
            const float t0 = ((gcx - acx) / aw) * 10.0f;
            const float t1 = ((gcy - acy) / ah) * 10.0f;
            const float t2 = logf(gw / aw) * 5.0f;
            const float t3 = logf(gh / ah) * 5.0f;
            const float4 rp = reinterpret_cast<const float4*>(reg)[(size_t)b * A_ + a];
            rsum = smooth_l1(fabsf(t0 - rp.x))
                 + smooth_l1(fabsf(t1 - rp.y))
                 + smooth_l1(fabsf(t2 - rp.z))
                 + smooth_l1(fabsf(t3 - rp.w));
            npos = 1.0f;
            // --- cls correction for the single target class ---
            const float p = clampp(cls[((size_t)b * A_ + a) * C_ + code]);
            acc = f_pos(p) - f_neg(p);   // phase 2 adds f_neg for every class
        } else if (best >= 0.4f) {
            mask = 0.0f;                 // ignore band: whole row contributes 0
        }
        s_mask[tid] = mask;
    }
    __syncthreads();

    // ---------------- Phase 2: branchless streaming focal sum ----------------
    const vfloat4* cp = reinterpret_cast<const vfloat4*>(cls) + ((size_t)b * A_ + a0) * C4;
    const int total = na * C4;
    #pragma unroll 4
    for (int t = tid; t < total; t += APB) {
        const int la = t / C4;
        const float m = s_mask[la];
        const vfloat4 v = __builtin_nontemporal_load(&cp[t]);  // zero-reuse stream
        float s = f_neg(clampp(v.x));
        s += f_neg(clampp(v.y));
        s += f_neg(clampp(v.z));
        s += f_neg(clampp(v.w));
        acc = fmaf(m, s, acc);
    }

    // ---------------- Block reduction: wave shuffle -> LDS -> ONE slot write ---
    #pragma unroll
    for (int off = 32; off > 0; off >>= 1) {
        acc  += __shfl_down(acc,  off, 64);
        rsum += __shfl_down(rsum, off, 64);
        npos += __shfl_down(npos, off, 64);
    }
    const int wv = tid >> 6;
    if ((tid & 63) == 0) {
        s_red[0][wv] = acc;
        s_red[1][wv] = rsum;
        s_red[2][wv] = npos;
    }
    __syncthreads();
    if (tid == 0) {
        const int slot = b * GX + blockIdx.x;
        P_cls[slot] = s_red[0][0] + s_red[0][1] + s_red[0][2] + s_red[0][3];
        P_reg[slot] = s_red[1][0] + s_red[1][1] + s_red[1][2] + s_red[1][3];
        P_np [slot] = s_red[2][0] + s_red[2][1] + s_red[2][2] + s_red[2][3];
    }
}

__global__ __launch_bounds__(1024) void focal_finalize(
    const float* __restrict__ P_cls,
    const float* __restrict__ P_reg,
    const float* __restrict__ P_np,
    float* __restrict__ out)
{
    __shared__ float red[3][16];
    const int tid  = threadIdx.x;
    const int lane = tid & 63;
    const int wv   = tid >> 6;
    float cm = 0.0f, rm = 0.0f;    // only tid 0's copies matter

    for (int b = 0; b < B_; ++b) {
        float c = 0.0f, r = 0.0f, n = 0.0f;
        for (int x = tid; x < GX; x += 1024) {
            c += P_cls[b * GX + x];
            r += P_reg[b * GX + x];
            n += P_np [b * GX + x];
        }
        #pragma unroll
        for (int off = 32; off > 0; off >>= 1) {
            c += __shfl_down(c, off, 64);
            r += __shfl_down(r, off, 64);
            n += __shfl_down(n, off, 64);
        }
        if (lane == 0) { red[0][wv] = c; red[1][wv] = r; red[2][wv] = n; }
        __syncthreads();
        if (tid == 0) {
            float cs = 0.0f, rs = 0.0f, ns = 0.0f;
            #pragma unroll
            for (int w = 0; w < 16; ++w) { cs += red[0][w]; rs += red[1][w]; ns += red[2][w]; }
            cm += cs / fmaxf(ns, 1.0f);
            rm += (ns > 0.0f) ? rs / fmaxf(4.0f * ns, 1.0f) : 0.0f;
        }
        __syncthreads();
    }
    if (tid == 0) {
        out[0] = cm / (float)B_;
        out[1] = rm / (float)B_;
    }
}

extern "C" void kernel_launch(void* const* d_in, const int* in_sizes, int n_in,
                              void* d_out, int out_size, void* d_ws, size_t ws_size,
                              hipStream_t stream) {
    const float* cls = (const float*)d_in[0];   // [B,A,C]
    const float* reg = (const float*)d_in[1];   // [B,A,4]
    const float* anc = (const float*)d_in[2];   // [1,A,4]
    const float* ann = (const float*)d_in[3];   // [B,M,5]
    float* out = (float*)d_out;

    float* wsf   = (float*)d_ws;
    float* P_cls = wsf;                 // B*GX floats
    float* P_reg = wsf + B_ * GX;       // B*GX floats
    float* P_np  = wsf + 2 * B_ * GX;   // B*GX floats

    dim3 grid(GX, B_);
    focal_fused<<<grid, APB, 0, stream>>>(cls, reg, anc, ann, P_cls, P_reg, P_np);
    focal_finalize<<<1, 1024, 0, stream>>>(P_cls, P_reg, P_np, out);
}